// Round 3
// baseline (381.716 us; speedup 1.0000x reference)
//
#include <hip/hip_runtime.h>

#define NEG_SLOPE 0.2f
#define CAP 64        // padded bucket capacity per node (max degree ~45 for Pois(16); guarded)
#define NPART 8       // dst-range partitions, pinned to XCDs via blockIdx % 8

typedef __attribute__((ext_vector_type(8))) short short8;
typedef __attribute__((ext_vector_type(4))) float f32x4;

__device__ __forceinline__ float lrelu(float x) {
    return x > 0.0f ? x : NEG_SLOPE * x;
}

// fp32 -> bf16 round-to-nearest-even (scalar path, epilogue only)
__device__ __forceinline__ unsigned short f2bf(float f) {
    unsigned int u = __float_as_uint(f);
    u += 0x7FFFu + ((u >> 16) & 1u);
    return (unsigned short)(u >> 16);
}

// packed RNE fp32-pair -> bf16x2 (low = first operand); identical rounding to f2bf
__device__ __forceinline__ unsigned int cvtpk(float lo, float hi) {
    unsigned int r;
    asm("v_cvt_pk_bf16_f32 %0, %1, %2" : "=v"(r) : "v"(lo), "v"(hi));
    return r;
}

// packed pair of bf16 (low ushort = first element) -> float2
__device__ __forceinline__ float2 bfpair(unsigned int u) {
    float2 r;
    r.x = __uint_as_float(u << 16);
    r.y = __uint_as_float(u & 0xFFFF0000u);
    return r;
}

// Streaming converter: writes BOTH operands of the GEMM in MFMA fragment order
// so the GEMM does zero conversion and only lane-consecutive dwordx4 loads.
//   xbf[((tile*8+ks)*64 + lane)*8 + j] = bf16(x[tile*16+(lane&15)][ks*32+(lane>>4)*8+j])
//     read: per (tile,ks) a wave consumes 16 rows x 128 B  -> 16 full lines, no overfetch
//     write: wave-linear 1 KB bursts, fully coalesced
//   Wtf[((t*8+ks)*64 + lane)*8 + j] = bf16(W[(ks*32+(lane>>4)*8+j)*128 + t*16+(lane&15)])
__global__ __launch_bounds__(256) void conv_kernel(
    const float* __restrict__ x, const float* __restrict__ W,
    unsigned short* __restrict__ xbf, unsigned short* __restrict__ Wtf,
    int n, int ntiles) {
    int u = blockIdx.x * 256 + threadIdx.x;
    int Tx = ntiles * 512;               // x tasks (each task = 8 bf16 out)
    if (u < Tx) {
        int lane = u & 63;
        int ks = (u >> 6) & 7;
        int tile = u >> 9;
        int row = tile * 16 + (lane & 15);
        if (row >= n) row = n - 1;
        int k0 = ks * 32 + (lane >> 4) * 8;
        const float* xp = &x[(size_t)row * 256 + k0];
        float4 a = *(const float4*)xp;
        float4 b = *(const float4*)(xp + 4);
        uint4 o;
        o.x = cvtpk(a.x, a.y);
        o.y = cvtpk(a.z, a.w);
        o.z = cvtpk(b.x, b.y);
        o.w = cvtpk(b.z, b.w);
        *(uint4*)&xbf[(size_t)u * 8] = o;
    } else if (u < Tx + 4096) {          // W tasks: 4096 * 8 = 32768 bf16
        int v = u - Tx;
        int lane = v & 63;
        int f = v >> 6;                  // 0..63
        int t = f >> 3;
        int ks = f & 7;
        int nn = t * 16 + (lane & 15);
        int kb = ks * 32 + (lane >> 4) * 8;
        const float* wp = &W[(size_t)kb * 128 + nn];
        float w0 = wp[0 * 128], w1 = wp[1 * 128], w2 = wp[2 * 128], w3 = wp[3 * 128];
        float w4 = wp[4 * 128], w5 = wp[5 * 128], w6 = wp[6 * 128], w7 = wp[7 * 128];
        uint4 o;
        o.x = cvtpk(w0, w1);
        o.y = cvtpk(w2, w3);
        o.z = cvtpk(w4, w5);
        o.w = cvtpk(w6, w7);
        *(uint4*)&Wtf[v * 8] = o;
    }
}

// GEMM: h_bf16[N,128] = bf16(x @ W) + fused a_src/a_dst epilogue.
// A-frags from xbf (global, coalesced dwordx4, HBM ~51 MB), B-frags from Wtf
// (global, 64 KB, L2-resident). No LDS, no conversions in the loop.
__global__ __launch_bounds__(256) void gemm_fused_kernel(
    const unsigned short* __restrict__ xbf, const unsigned short* __restrict__ Wtf,
    const float* __restrict__ att_src, const float* __restrict__ att_dst,
    unsigned short* __restrict__ hb, float* __restrict__ a_src,
    float* __restrict__ a_dst, int n, int ntiles) {
    int tid = threadIdx.x;
    int wave = tid >> 6;
    int lane = tid & 63;
    int ln = lane & 15;
    int quad = lane >> 4;
    int row0w = blockIdx.x * 128 + wave * 32;

    int t0 = blockIdx.x * 8 + wave * 2;      // 16-row tile indices
    int t1 = t0 + 1;
    if (t0 >= ntiles) t0 = ntiles - 1;       // tail: duplicate compute, guarded store
    if (t1 >= ntiles) t1 = ntiles - 1;

    f32x4 acc[2][8];
    #pragma unroll
    for (int rt = 0; rt < 2; ++rt)
        #pragma unroll
        for (int t = 0; t < 8; ++t) acc[rt][t] = (f32x4){0.f, 0.f, 0.f, 0.f};

    #pragma unroll
    for (int ks = 0; ks < 8; ++ks) {
        short8 af0 = *(const short8*)&xbf[(size_t)((t0 * 8 + ks) * 64 + lane) * 8];
        short8 af1 = *(const short8*)&xbf[(size_t)((t1 * 8 + ks) * 64 + lane) * 8];
        #pragma unroll
        for (int t = 0; t < 8; ++t) {
            short8 bf = *(const short8*)&Wtf[(size_t)(((t * 8 + ks) * 64) + lane) * 8];
            acc[0][t] = __builtin_amdgcn_mfma_f32_16x16x32_bf16(af0, bf, acc[0][t], 0, 0, 0);
            acc[1][t] = __builtin_amdgcn_mfma_f32_16x16x32_bf16(af1, bf, acc[1][t], 0, 0, 0);
        }
    }

    // h store: C/D layout col = t*16+ln, row = rt*16 + quad*4 + r
    #pragma unroll
    for (int rt = 0; rt < 2; ++rt) {
        #pragma unroll
        for (int t = 0; t < 8; ++t) {
            #pragma unroll
            for (int r = 0; r < 4; ++r) {
                int grow = row0w + rt * 16 + quad * 4 + r;
                if (grow < n) hb[(size_t)grow * 128 + t * 16 + ln] = f2bf(acc[rt][t][r]);
            }
        }
    }

    // fused attention halves
    #pragma unroll
    for (int hd = 0; hd < 4; ++hd) {
        float as1 = att_src[hd * 32 + ln];
        float as2 = att_src[hd * 32 + 16 + ln];
        float ad1 = att_dst[hd * 32 + ln];
        float ad2 = att_dst[hd * 32 + 16 + ln];
        #pragma unroll
        for (int rt = 0; rt < 2; ++rt) {
            #pragma unroll
            for (int r = 0; r < 4; ++r) {
                float ps = acc[rt][2 * hd][r] * as1 + acc[rt][2 * hd + 1][r] * as2;
                float pd = acc[rt][2 * hd][r] * ad1 + acc[rt][2 * hd + 1][r] * ad2;
                #pragma unroll
                for (int off = 1; off < 16; off <<= 1) {
                    ps += __shfl_xor(ps, off);
                    pd += __shfl_xor(pd, off);
                }
                if (ln == 0) {
                    int grow = row0w + rt * 16 + quad * 4 + r;
                    if (grow < n) {
                        a_src[grow * 4 + hd] = ps;
                        a_dst[grow * 4 + hd] = pd;
                    }
                }
            }
        }
    }
}

// Fused hist + padded-bucket scatter, int4-vectorized edge reads.
// Exact round-0 structure (2048 blocks, full wave parallelism for atomics).
__global__ __launch_bounds__(256) void build_kernel(
    const int* __restrict__ src, const int* __restrict__ dst,
    int* __restrict__ deg, int* __restrict__ bucket, int e, int n) {
    int p = blockIdx.x & (NPART - 1);
    int slice = blockIdx.x >> 3;
    int nslices = gridDim.x >> 3;
    int part = (n + NPART - 1) / NPART;
    unsigned lo = (unsigned)(p * part);
    int e4 = e >> 2;
    int stride = nslices * 256;
    const int4* dst4 = (const int4*)dst;
    const int4* src4 = (const int4*)src;
    for (int i = slice * 256 + threadIdx.x; i < e4; i += stride) {
        int4 d4 = dst4[i];
        int4 s4 = src4[i];
        if ((unsigned)(d4.x - lo) < (unsigned)part) {
            int r = atomicAdd(&deg[d4.x], 1);
            if (r < CAP) bucket[d4.x * CAP + r] = s4.x;
        }
        if ((unsigned)(d4.y - lo) < (unsigned)part) {
            int r = atomicAdd(&deg[d4.y], 1);
            if (r < CAP) bucket[d4.y * CAP + r] = s4.y;
        }
        if ((unsigned)(d4.z - lo) < (unsigned)part) {
            int r = atomicAdd(&deg[d4.z], 1);
            if (r < CAP) bucket[d4.z * CAP + r] = s4.z;
        }
        if ((unsigned)(d4.w - lo) < (unsigned)part) {
            int r = atomicAdd(&deg[d4.w], 1);
            if (r < CAP) bucket[d4.w * CAP + r] = s4.w;
        }
    }
    if (blockIdx.x == 0 && threadIdx.x < (e & 3)) {
        int i = e4 * 4 + threadIdx.x;
        int d = dst[i];
        int r = atomicAdd(&deg[d], 1);
        if (r < CAP) bucket[d * CAP + r] = src[i];
    }
}

// One wave per destination node, two-phase.
// Phase 1: lane = (el=lane&15, hh=lane>>4) computes each logit once, reduces
// max/sum via shfl_xor over 16 el-lanes, writes normalized alpha + ids to LDS.
// Phase 2: pure gather+FMA, unrolled x8 for MLP.
__global__ __launch_bounds__(256) void aggregate_kernel(
    const unsigned short* __restrict__ hb, const float* __restrict__ a_src,
    const float* __restrict__ a_dst, const int* __restrict__ deg,
    const int* __restrict__ bucket, const float* __restrict__ bias,
    float* __restrict__ out, int n) {
    __shared__ float lds_alpha[4][CAP][4];  // [wave][edge][head]
    __shared__ int lds_s[4][CAP];
    int wave = threadIdx.x >> 6;
    int lane = threadIdx.x & 63;
    int node = blockIdx.x * 4 + wave;
    if (node >= n) node = n - 1;  // duplicate tail work; keeps barrier safe
    int el = lane & 15;
    int hh = lane >> 4;

    int cnt = deg[node];
    if (cnt > CAP) cnt = CAP;

    float adst = a_dst[node * 4 + hh];
    float e_self = lrelu(a_src[node * 4 + hh] + adst);

    float e_gp[4];
    int s_gp[4];
    float mloc = e_self;
    #pragma unroll
    for (int g = 0; g < 4; ++g) {
        int p = g * 16 + el;
        if (p < cnt) {
            int s = bucket[(unsigned)node * CAP + p];
            s_gp[g] = s;
            float ev = lrelu(a_src[s * 4 + hh] + adst);
            e_gp[g] = ev;
            mloc = fmaxf(mloc, ev);
        } else {
            s_gp[g] = node;
            e_gp[g] = -INFINITY;
        }
    }
    #pragma unroll
    for (int off = 1; off < 16; off <<= 1)
        mloc = fmaxf(mloc, __shfl_xor(mloc, off));

    float pe_gp[4];
    float dloc = 0.0f;
    #pragma unroll
    for (int g = 0; g < 4; ++g) {
        float pe = __expf(e_gp[g] - mloc);  // exp(-inf)=0 for masked slots
        pe_gp[g] = pe;
        dloc += pe;
    }
    #pragma unroll
    for (int off = 1; off < 16; off <<= 1)
        dloc += __shfl_xor(dloc, off);

    float pe_self = __expf(e_self - mloc);
    float inv = 1.0f / (dloc + pe_self);
    float alpha_self = pe_self * inv;

    #pragma unroll
    for (int g = 0; g < 4; ++g) {
        lds_alpha[wave][g * 16 + el][hh] = pe_gp[g] * inv;
        if (hh == 0) lds_s[wave][g * 16 + el] = s_gp[g];
    }
    __syncthreads();

    const unsigned int* hbu = (const unsigned int*)hb;
    float2 acc;
    {
        float2 hv = bfpair(hbu[(unsigned)node * 64u + lane]);
        acc.x = alpha_self * hv.x;
        acc.y = alpha_self * hv.y;
    }
    int p = 0;
    for (; p + 8 <= cnt; p += 8) {
        int4 sA = *(const int4*)&lds_s[wave][p];
        int4 sB = *(const int4*)&lds_s[wave][p + 4];
        unsigned int v0 = hbu[(unsigned)sA.x * 64u + lane];
        unsigned int v1 = hbu[(unsigned)sA.y * 64u + lane];
        unsigned int v2 = hbu[(unsigned)sA.z * 64u + lane];
        unsigned int v3 = hbu[(unsigned)sA.w * 64u + lane];
        unsigned int v4 = hbu[(unsigned)sB.x * 64u + lane];
        unsigned int v5 = hbu[(unsigned)sB.y * 64u + lane];
        unsigned int v6 = hbu[(unsigned)sB.z * 64u + lane];
        unsigned int v7 = hbu[(unsigned)sB.w * 64u + lane];
        float al0 = lds_alpha[wave][p + 0][hh];
        float al1 = lds_alpha[wave][p + 1][hh];
        float al2 = lds_alpha[wave][p + 2][hh];
        float al3 = lds_alpha[wave][p + 3][hh];
        float al4 = lds_alpha[wave][p + 4][hh];
        float al5 = lds_alpha[wave][p + 5][hh];
        float al6 = lds_alpha[wave][p + 6][hh];
        float al7 = lds_alpha[wave][p + 7][hh];
        float2 h0 = bfpair(v0), h1 = bfpair(v1), h2 = bfpair(v2), h3 = bfpair(v3);
        float2 h4 = bfpair(v4), h5 = bfpair(v5), h6 = bfpair(v6), h7 = bfpair(v7);
        acc.x += al0 * h0.x + al1 * h1.x + al2 * h2.x + al3 * h3.x
               + al4 * h4.x + al5 * h5.x + al6 * h6.x + al7 * h7.x;
        acc.y += al0 * h0.y + al1 * h1.y + al2 * h2.y + al3 * h3.y
               + al4 * h4.y + al5 * h5.y + al6 * h6.y + al7 * h7.y;
    }
    for (; p + 4 <= cnt; p += 4) {
        int4 sA = *(const int4*)&lds_s[wave][p];
        unsigned int v0 = hbu[(unsigned)sA.x * 64u + lane];
        unsigned int v1 = hbu[(unsigned)sA.y * 64u + lane];
        unsigned int v2 = hbu[(unsigned)sA.z * 64u + lane];
        unsigned int v3 = hbu[(unsigned)sA.w * 64u + lane];
        float al0 = lds_alpha[wave][p + 0][hh];
        float al1 = lds_alpha[wave][p + 1][hh];
        float al2 = lds_alpha[wave][p + 2][hh];
        float al3 = lds_alpha[wave][p + 3][hh];
        float2 h0 = bfpair(v0), h1 = bfpair(v1), h2 = bfpair(v2), h3 = bfpair(v3);
        acc.x += al0 * h0.x + al1 * h1.x + al2 * h2.x + al3 * h3.x;
        acc.y += al0 * h0.y + al1 * h1.y + al2 * h2.y + al3 * h3.y;
    }
    for (; p < cnt; ++p) {
        int s = lds_s[wave][p];
        float al = lds_alpha[wave][p][hh];
        float2 hv = bfpair(hbu[(unsigned)s * 64u + lane]);
        acc.x += al * hv.x;
        acc.y += al * hv.y;
    }

    int oc = hh * 32 + el * 2;
    float2 b2 = *(const float2*)&bias[oc];
    float2 o;
    o.x = acc.x + b2.x;
    o.y = acc.y + b2.y;
    *(float2*)&out[(size_t)node * 128 + oc] = o;
}

extern "C" void kernel_launch(void* const* d_in, const int* in_sizes, int n_in,
                              void* d_out, int out_size, void* d_ws, size_t ws_size,
                              hipStream_t stream) {
    const float* x = (const float*)d_in[0];
    const int* edge_index = (const int*)d_in[1];
    const float* W = (const float*)d_in[2];
    const float* att_src = (const float*)d_in[3];
    const float* att_dst = (const float*)d_in[4];
    const float* bias = (const float*)d_in[5];
    float* out = (float*)d_out;

    int n = in_sizes[0] / 256;   // 100000
    int e = in_sizes[1] / 2;     // 1600000
    const int* esrc = edge_index;
    const int* edst = edge_index + e;
    int ntiles = (n + 15) / 16;

    // workspace layout
    char* w = (char*)d_ws;
    unsigned short* hb = (unsigned short*)w;  w += (size_t)n * 128 * 2;        // bf16 h
    float* a_src = (float*)w;                 w += (size_t)n * 4 * 4;
    float* a_dst = (float*)w;                 w += (size_t)n * 4 * 4;
    unsigned short* Wtf = (unsigned short*)w; w += 128 * 256 * 2;
    int* deg = (int*)w;                       w += (size_t)n * 4;
    int* bucket = (int*)w;                    w += (size_t)n * CAP * 4;
    unsigned short* xbf = (unsigned short*)w; w += (size_t)ntiles * 512 * 8 * 2; // bf16 x, frag order

    hipMemsetAsync(deg, 0, (size_t)n * sizeof(int), stream);

    int Tx = ntiles * 512;
    conv_kernel<<<(Tx + 4096 + 255) / 256, 256, 0, stream>>>(x, W, xbf, Wtf, n, ntiles);
    build_kernel<<<256 * NPART, 256, 0, stream>>>(esrc, edst, deg, bucket, e, n);
    gemm_fused_kernel<<<(n + 127) / 128, 256, 0, stream>>>(xbf, Wtf, att_src, att_dst,
                                                           hb, a_src, a_dst, n, ntiles);
    aggregate_kernel<<<(n + 3) / 4, 256, 0, stream>>>(hb, a_src, a_dst, deg,
                                                      bucket, bias, out, n);
}

// Round 4
// 354.580 us; speedup vs baseline: 1.0765x; 1.0765x over previous
//
#include <hip/hip_runtime.h>

#define NEG_SLOPE 0.2f
#define CAP 64      // padded bucket capacity per node (max degree ~45 for Pois(16); guarded)
#define NPART 8     // dst-range partitions, pinned to XCDs via blockIdx % 8

typedef __attribute__((ext_vector_type(8))) short short8;
typedef __attribute__((ext_vector_type(4))) float f32x4;
typedef __attribute__((ext_vector_type(4))) unsigned int u32x4;

__device__ __forceinline__ float lrelu(float x) {
    return x > 0.0f ? x : NEG_SLOPE * x;
}

// fp32 -> bf16 round-to-nearest-even (host-side-equivalent scalar path)
__device__ __forceinline__ unsigned short f2bf(float f) {
    unsigned int u = __float_as_uint(f);
    u += 0x7FFFu + ((u >> 16) & 1u);
    return (unsigned short)(u >> 16);
}

// packed RNE fp32-pair -> bf16x2 (low ushort = first operand); identical rounding to f2bf
__device__ __forceinline__ unsigned int cvtpk(float lo, float hi) {
    unsigned int r;
    asm("v_cvt_pk_bf16_f32 %0, %1, %2" : "=v"(r) : "v"(lo), "v"(hi));
    return r;
}

// packed pair of bf16 (low ushort = first element) -> float2
__device__ __forceinline__ float2 bfpair(unsigned int u) {
    float2 r;
    r.x = __uint_as_float(u << 16);
    r.y = __uint_as_float(u & 0xFFFF0000u);
    return r;
}

// W[256][128] fp32 -> Wtf in MFMA B-fragment order:
// Wtf[((t*8+ks)*64 + lane)*8 + j] = bf16(W[(ks*32 + (lane>>4)*8 + j)*128 + t*16 + (lane&15)])
// so a bfrag read is one lane-consecutive dwordx4 (and LDS-staged copy is linear).
// Also zeroes deg[] (replaces the hipMemsetAsync dispatch).
__global__ void convW_kernel(const float* __restrict__ W, unsigned short* __restrict__ Wtf,
                             int* __restrict__ deg, int n) {
    int idx = blockIdx.x * blockDim.x + threadIdx.x;  // 32768
    int j = idx & 7;
    int lane = (idx >> 3) & 63;
    int f = idx >> 9;          // 0..63
    int t = f >> 3;
    int ks = f & 7;
    int k = ks * 32 + (lane >> 4) * 8 + j;
    int nn = t * 16 + (lane & 15);
    Wtf[idx] = f2bf(W[k * 128 + nn]);
    for (int z = idx; z < n; z += 32768) deg[z] = 0;
}

// Fused: h_bf16[N,128] = bf16(x @ W); a_src[N,4], a_dst[N,4] from fp32 accumulators.
// Round-0 structure: FULL W (64 KB, bf16, fragment order) staged in LDS once per
// block; A-frags direct from global x (L3-resident). Wave computes 2 row-tiles
// (32 rows) sharing each bfrag ds_read.
// This round: in-loop fp32->bf16 via v_cvt_pk_bf16_f32 (8 instrs/ks vs ~64 with
// manual RNE) and packed 4-B h-stores via shfl-pairing (both RNE-identical).
__global__ __launch_bounds__(256) void gemm_fused_kernel(
    const float* __restrict__ x, const unsigned short* __restrict__ Wtf,
    const float* __restrict__ att_src, const float* __restrict__ att_dst,
    unsigned short* __restrict__ hb, float* __restrict__ a_src,
    float* __restrict__ a_dst, int n) {
    __shared__ unsigned short Bs[32768];  // 64 KB
    int tid = threadIdx.x;

    // stage Wtf -> Bs linearly: 16 iters x 256 thr x 16 B (coalesced dwordx4)
    #pragma unroll
    for (int it = 0; it < 16; ++it) {
        int o = (it * 256 + tid) * 8;
        *(short8*)&Bs[o] = *(const short8*)&Wtf[o];
    }
    __syncthreads();

    int wave = tid >> 6;
    int lane = tid & 63;
    int ln = lane & 15;
    int quad = lane >> 4;
    int row0w = blockIdx.x * 128 + wave * 32;

    int r0 = row0w + ln;       if (r0 >= n) r0 = n - 1;
    int r1 = row0w + 16 + ln;  if (r1 >= n) r1 = n - 1;
    const float* xr0 = &x[(size_t)r0 * 256];
    const float* xr1 = &x[(size_t)r1 * 256];

    f32x4 acc[2][8];
    #pragma unroll
    for (int rt = 0; rt < 2; ++rt)
        #pragma unroll
        for (int t = 0; t < 8; ++t) acc[rt][t] = (f32x4){0.f, 0.f, 0.f, 0.f};

    #pragma unroll
    for (int ks = 0; ks < 8; ++ks) {
        int ko = ks * 32 + quad * 8;
        float4 a00 = *(const float4*)&xr0[ko];
        float4 a01 = *(const float4*)&xr0[ko + 4];
        float4 a10 = *(const float4*)&xr1[ko];
        float4 a11 = *(const float4*)&xr1[ko + 4];
        u32x4 u0, u1;
        u0.x = cvtpk(a00.x, a00.y);
        u0.y = cvtpk(a00.z, a00.w);
        u0.z = cvtpk(a01.x, a01.y);
        u0.w = cvtpk(a01.z, a01.w);
        u1.x = cvtpk(a10.x, a10.y);
        u1.y = cvtpk(a10.z, a10.w);
        u1.z = cvtpk(a11.x, a11.y);
        u1.w = cvtpk(a11.z, a11.w);
        short8 af0 = __builtin_bit_cast(short8, u0);
        short8 af1 = __builtin_bit_cast(short8, u1);
        #pragma unroll
        for (int t = 0; t < 8; ++t) {
            short8 bf = *(const short8*)&Bs[(((t * 8 + ks) * 64) + lane) * 8];
            acc[0][t] = __builtin_amdgcn_mfma_f32_16x16x32_bf16(af0, bf, acc[0][t], 0, 0, 0);
            acc[1][t] = __builtin_amdgcn_mfma_f32_16x16x32_bf16(af1, bf, acc[1][t], 0, 0, 0);
        }
    }

    // h store: C/D layout col = t*16+ln, row = rt*16 + quad*4 + r.
    // Pair adjacent cols (ln even with ln+1, same quad) via shfl_down, store 4 B.
    bool evenln = (ln & 1) == 0;
    #pragma unroll
    for (int rt = 0; rt < 2; ++rt) {
        #pragma unroll
        for (int t = 0; t < 8; ++t) {
            #pragma unroll
            for (int r = 0; r < 4; ++r) {
                float v = acc[rt][t][r];
                float vn = __shfl_down(v, 1);
                int grow = row0w + rt * 16 + quad * 4 + r;
                if (evenln && grow < n) {
                    unsigned int pk = cvtpk(v, vn);
                    *(unsigned int*)&hb[(size_t)grow * 128 + t * 16 + ln] = pk;
                }
            }
        }
    }

    // fused attention halves
    #pragma unroll
    for (int hd = 0; hd < 4; ++hd) {
        float as1 = att_src[hd * 32 + ln];
        float as2 = att_src[hd * 32 + 16 + ln];
        float ad1 = att_dst[hd * 32 + ln];
        float ad2 = att_dst[hd * 32 + 16 + ln];
        #pragma unroll
        for (int rt = 0; rt < 2; ++rt) {
            #pragma unroll
            for (int r = 0; r < 4; ++r) {
                float ps = acc[rt][2 * hd][r] * as1 + acc[rt][2 * hd + 1][r] * as2;
                float pd = acc[rt][2 * hd][r] * ad1 + acc[rt][2 * hd + 1][r] * ad2;
                #pragma unroll
                for (int off = 1; off < 16; off <<= 1) {
                    ps += __shfl_xor(ps, off);
                    pd += __shfl_xor(pd, off);
                }
                if (ln == 0) {
                    int grow = row0w + rt * 16 + quad * 4 + r;
                    if (grow < n) {
                        a_src[grow * 4 + hd] = ps;
                        a_dst[grow * 4 + hd] = pd;
                    }
                }
            }
        }
    }
}

// Fused hist + padded-bucket scatter, int4-vectorized edge reads.
__global__ __launch_bounds__(256) void build_kernel(
    const int* __restrict__ src, const int* __restrict__ dst,
    int* __restrict__ deg, int* __restrict__ bucket, int e, int n) {
    int p = blockIdx.x & (NPART - 1);
    int slice = blockIdx.x >> 3;
    int nslices = gridDim.x >> 3;
    int part = (n + NPART - 1) / NPART;
    unsigned lo = (unsigned)(p * part);
    int e4 = e >> 2;
    int stride = nslices * 256;
    const int4* dst4 = (const int4*)dst;
    const int4* src4 = (const int4*)src;
    for (int i = slice * 256 + threadIdx.x; i < e4; i += stride) {
        int4 d4 = dst4[i];
        int4 s4 = src4[i];
        if ((unsigned)(d4.x - lo) < (unsigned)part) {
            int r = atomicAdd(&deg[d4.x], 1);
            if (r < CAP) bucket[d4.x * CAP + r] = s4.x;
        }
        if ((unsigned)(d4.y - lo) < (unsigned)part) {
            int r = atomicAdd(&deg[d4.y], 1);
            if (r < CAP) bucket[d4.y * CAP + r] = s4.y;
        }
        if ((unsigned)(d4.z - lo) < (unsigned)part) {
            int r = atomicAdd(&deg[d4.z], 1);
            if (r < CAP) bucket[d4.z * CAP + r] = s4.z;
        }
        if ((unsigned)(d4.w - lo) < (unsigned)part) {
            int r = atomicAdd(&deg[d4.w], 1);
            if (r < CAP) bucket[d4.w * CAP + r] = s4.w;
        }
    }
    if (blockIdx.x == 0 && threadIdx.x < (e & 3)) {
        int i = e4 * 4 + threadIdx.x;
        int d = dst[i];
        int r = atomicAdd(&deg[d], 1);
        if (r < CAP) bucket[d * CAP + r] = src[i];
    }
}

// One wave per destination node, two-phase.
// Phase 1: lane = (el=lane&15, hh=lane>>4) computes each logit once, reduces
// max/sum via shfl_xor over 16 el-lanes, writes normalized alpha + ids to LDS.
// Phase 2: pure gather+FMA, unrolled x8 for MLP.
__global__ __launch_bounds__(256) void aggregate_kernel(
    const unsigned short* __restrict__ hb, const float* __restrict__ a_src,
    const float* __restrict__ a_dst, const int* __restrict__ deg,
    const int* __restrict__ bucket, const float* __restrict__ bias,
    float* __restrict__ out, int n) {
    __shared__ float lds_alpha[4][CAP][4];  // [wave][edge][head]
    __shared__ int lds_s[4][CAP];
    int wave = threadIdx.x >> 6;
    int lane = threadIdx.x & 63;
    int node = blockIdx.x * 4 + wave;
    if (node >= n) node = n - 1;  // duplicate tail work; keeps barrier safe
    int el = lane & 15;
    int hh = lane >> 4;

    int cnt = deg[node];
    if (cnt > CAP) cnt = CAP;

    float adst = a_dst[node * 4 + hh];
    float e_self = lrelu(a_src[node * 4 + hh] + adst);

    float e_gp[4];
    int s_gp[4];
    float mloc = e_self;
    #pragma unroll
    for (int g = 0; g < 4; ++g) {
        int p = g * 16 + el;
        if (p < cnt) {
            int s = bucket[(unsigned)node * CAP + p];
            s_gp[g] = s;
            float ev = lrelu(a_src[s * 4 + hh] + adst);
            e_gp[g] = ev;
            mloc = fmaxf(mloc, ev);
        } else {
            s_gp[g] = node;
            e_gp[g] = -INFINITY;
        }
    }
    #pragma unroll
    for (int off = 1; off < 16; off <<= 1)
        mloc = fmaxf(mloc, __shfl_xor(mloc, off));

    float pe_gp[4];
    float dloc = 0.0f;
    #pragma unroll
    for (int g = 0; g < 4; ++g) {
        float pe = __expf(e_gp[g] - mloc);  // exp(-inf)=0 for masked slots
        pe_gp[g] = pe;
        dloc += pe;
    }
    #pragma unroll
    for (int off = 1; off < 16; off <<= 1)
        dloc += __shfl_xor(dloc, off);

    float pe_self = __expf(e_self - mloc);
    float inv = 1.0f / (dloc + pe_self);
    float alpha_self = pe_self * inv;

    #pragma unroll
    for (int g = 0; g < 4; ++g) {
        lds_alpha[wave][g * 16 + el][hh] = pe_gp[g] * inv;
        if (hh == 0) lds_s[wave][g * 16 + el] = s_gp[g];
    }
    __syncthreads();

    const unsigned int* hbu = (const unsigned int*)hb;
    float2 acc;
    {
        float2 hv = bfpair(hbu[(unsigned)node * 64u + lane]);
        acc.x = alpha_self * hv.x;
        acc.y = alpha_self * hv.y;
    }
    int p = 0;
    for (; p + 8 <= cnt; p += 8) {
        int4 sA = *(const int4*)&lds_s[wave][p];
        int4 sB = *(const int4*)&lds_s[wave][p + 4];
        unsigned int v0 = hbu[(unsigned)sA.x * 64u + lane];
        unsigned int v1 = hbu[(unsigned)sA.y * 64u + lane];
        unsigned int v2 = hbu[(unsigned)sA.z * 64u + lane];
        unsigned int v3 = hbu[(unsigned)sA.w * 64u + lane];
        unsigned int v4 = hbu[(unsigned)sB.x * 64u + lane];
        unsigned int v5 = hbu[(unsigned)sB.y * 64u + lane];
        unsigned int v6 = hbu[(unsigned)sB.z * 64u + lane];
        unsigned int v7 = hbu[(unsigned)sB.w * 64u + lane];
        float al0 = lds_alpha[wave][p + 0][hh];
        float al1 = lds_alpha[wave][p + 1][hh];
        float al2 = lds_alpha[wave][p + 2][hh];
        float al3 = lds_alpha[wave][p + 3][hh];
        float al4 = lds_alpha[wave][p + 4][hh];
        float al5 = lds_alpha[wave][p + 5][hh];
        float al6 = lds_alpha[wave][p + 6][hh];
        float al7 = lds_alpha[wave][p + 7][hh];
        float2 h0 = bfpair(v0), h1 = bfpair(v1), h2 = bfpair(v2), h3 = bfpair(v3);
        float2 h4 = bfpair(v4), h5 = bfpair(v5), h6 = bfpair(v6), h7 = bfpair(v7);
        acc.x += al0 * h0.x + al1 * h1.x + al2 * h2.x + al3 * h3.x
               + al4 * h4.x + al5 * h5.x + al6 * h6.x + al7 * h7.x;
        acc.y += al0 * h0.y + al1 * h1.y + al2 * h2.y + al3 * h3.y
               + al4 * h4.y + al5 * h5.y + al6 * h6.y + al7 * h7.y;
    }
    for (; p + 4 <= cnt; p += 4) {
        int4 sA = *(const int4*)&lds_s[wave][p];
        unsigned int v0 = hbu[(unsigned)sA.x * 64u + lane];
        unsigned int v1 = hbu[(unsigned)sA.y * 64u + lane];
        unsigned int v2 = hbu[(unsigned)sA.z * 64u + lane];
        unsigned int v3 = hbu[(unsigned)sA.w * 64u + lane];
        float al0 = lds_alpha[wave][p + 0][hh];
        float al1 = lds_alpha[wave][p + 1][hh];
        float al2 = lds_alpha[wave][p + 2][hh];
        float al3 = lds_alpha[wave][p + 3][hh];
        float2 h0 = bfpair(v0), h1 = bfpair(v1), h2 = bfpair(v2), h3 = bfpair(v3);
        acc.x += al0 * h0.x + al1 * h1.x + al2 * h2.x + al3 * h3.x;
        acc.y += al0 * h0.y + al1 * h1.y + al2 * h2.y + al3 * h3.y;
    }
    for (; p < cnt; ++p) {
        int s = lds_s[wave][p];
        float al = lds_alpha[wave][p][hh];
        float2 hv = bfpair(hbu[(unsigned)s * 64u + lane]);
        acc.x += al * hv.x;
        acc.y += al * hv.y;
    }

    int oc = hh * 32 + el * 2;
    float2 b2 = *(const float2*)&bias[oc];
    float2 o;
    o.x = acc.x + b2.x;
    o.y = acc.y + b2.y;
    *(float2*)&out[(size_t)node * 128 + oc] = o;
}

extern "C" void kernel_launch(void* const* d_in, const int* in_sizes, int n_in,
                              void* d_out, int out_size, void* d_ws, size_t ws_size,
                              hipStream_t stream) {
    const float* x = (const float*)d_in[0];
    const int* edge_index = (const int*)d_in[1];
    const float* W = (const float*)d_in[2];
    const float* att_src = (const float*)d_in[3];
    const float* att_dst = (const float*)d_in[4];
    const float* bias = (const float*)d_in[5];
    float* out = (float*)d_out;

    int n = in_sizes[0] / 256;   // 100000
    int e = in_sizes[1] / 2;     // 1600000
    const int* esrc = edge_index;
    const int* edst = edge_index + e;

    // workspace layout
    char* w = (char*)d_ws;
    unsigned short* hb = (unsigned short*)w;  w += (size_t)n * 128 * 2;   // bf16 h
    float* a_src = (float*)w;                 w += (size_t)n * 4 * 4;
    float* a_dst = (float*)w;                 w += (size_t)n * 4 * 4;
    unsigned short* Wtf = (unsigned short*)w; w += 128 * 256 * 2;
    int* deg = (int*)w;                       w += (size_t)n * 4;
    int* bucket = (int*)w;                    w += (size_t)n * CAP * 4;

    convW_kernel<<<128, 256, 0, stream>>>(W, Wtf, deg, n);
    gemm_fused_kernel<<<(n + 127) / 128, 256, 0, stream>>>(x, Wtf, att_src, att_dst,
                                                           hb, a_src, a_dst, n);
    build_kernel<<<256 * NPART, 256, 0, stream>>>(esrc, edst, deg, bucket, e, n);
    aggregate_kernel<<<(n + 3) / 4, 256, 0, stream>>>(hb, a_src, a_dst, deg,
                                                      bucket, bias, out, n);
}

// Round 6
// 352.301 us; speedup vs baseline: 1.0835x; 1.0065x over previous
//
#include <hip/hip_runtime.h>

#define NEG_SLOPE 0.2f
#define CAP 64      // padded bucket capacity per node (max degree ~45 for Pois(16); guarded)
#define NPART 8     // dst-range partitions, pinned to XCDs via blockIdx % 8

typedef __attribute__((ext_vector_type(8))) short short8;
typedef __attribute__((ext_vector_type(4))) float f32x4;
typedef __attribute__((ext_vector_type(4))) unsigned int u32x4;

__device__ __forceinline__ float lrelu(float x) {
    return x > 0.0f ? x : NEG_SLOPE * x;
}

// fp32 -> bf16 round-to-nearest-even (host-side-equivalent scalar path)
__device__ __forceinline__ unsigned short f2bf(float f) {
    unsigned int u = __float_as_uint(f);
    u += 0x7FFFu + ((u >> 16) & 1u);
    return (unsigned short)(u >> 16);
}

// packed RNE fp32-pair -> bf16x2 (low ushort = first operand); identical rounding to f2bf
__device__ __forceinline__ unsigned int cvtpk(float lo, float hi) {
    unsigned int r;
    asm("v_cvt_pk_bf16_f32 %0, %1, %2" : "=v"(r) : "v"(lo), "v"(hi));
    return r;
}

// packed pair of bf16 (low ushort = first element) -> float2
__device__ __forceinline__ float2 bfpair(unsigned int u) {
    float2 r;
    r.x = __uint_as_float(u << 16);
    r.y = __uint_as_float(u & 0xFFFF0000u);
    return r;
}

// W[256][128] fp32 -> Wtf in MFMA B-fragment order:
// Wtf[((t*8+ks)*64 + lane)*8 + j] = bf16(W[(ks*32 + (lane>>4)*8 + j)*128 + t*16 + (lane&15)])
// so a bfrag read is one lane-consecutive dwordx4 (and LDS-staged copy is linear).
// Also zeroes deg[] (replaces the hipMemsetAsync dispatch).
__global__ void convW_kernel(const float* __restrict__ W, unsigned short* __restrict__ Wtf,
                             int* __restrict__ deg, int n) {
    int idx = blockIdx.x * blockDim.x + threadIdx.x;  // 32768
    int j = idx & 7;
    int lane = (idx >> 3) & 63;
    int f = idx >> 9;          // 0..63
    int t = f >> 3;
    int ks = f & 7;
    int k = ks * 32 + (lane >> 4) * 8 + j;
    int nn = t * 16 + (lane & 15);
    Wtf[idx] = f2bf(W[k * 128 + nn]);
    for (int z = idx; z < n; z += 32768) deg[z] = 0;
}

// Fused: h_bf16[N,128] = bf16(x @ W); a_src[N,4], a_dst[N,4] from fp32 accumulators.
// Round-5: K-split LDS staging. W's fragment layout is t-major, so each tile t's
// ks-half is a contiguous 4 KB run; stage 32 KB (ks 0..3), compute, barrier,
// restage (ks 4..7), compute. LDS 64->32 KB lifts occupancy 2->4 blocks/CU
// (16 waves/CU) to hide the x-load latency that round-4 showed was the real
// gemm bottleneck (cvt_pk VALU cut was ~neutral).
__global__ __launch_bounds__(256, 4) void gemm_fused_kernel(
    const float* __restrict__ x, const unsigned short* __restrict__ Wtf,
    const float* __restrict__ att_src, const float* __restrict__ att_dst,
    unsigned short* __restrict__ hb, float* __restrict__ a_src,
    float* __restrict__ a_dst, int n) {
    __shared__ unsigned short Bs[16384];  // 32 KB = half of W in fragment order
    int tid = threadIdx.x;
    int wave = tid >> 6;
    int lane = tid & 63;
    int ln = lane & 15;
    int quad = lane >> 4;
    int row0w = blockIdx.x * 128 + wave * 32;

    int r0 = row0w + ln;       if (r0 >= n) r0 = n - 1;
    int r1 = row0w + 16 + ln;  if (r1 >= n) r1 = n - 1;
    const float* xr0 = &x[(size_t)r0 * 256];
    const float* xr1 = &x[(size_t)r1 * 256];

    f32x4 acc[2][8];
    #pragma unroll
    for (int rt = 0; rt < 2; ++rt)
        #pragma unroll
        for (int t = 0; t < 8; ++t) acc[rt][t] = (f32x4){0.f, 0.f, 0.f, 0.f};

    #pragma unroll
    for (int hf = 0; hf < 2; ++hf) {
        if (hf) __syncthreads();   // all waves done reading Bs half 0
        // stage half-K: for each tile t, ks in [hf*4, hf*4+4) is contiguous 4 KB
        // = 256 thr x 16 B exactly; 8 chunks, fully coalesced dwordx4.
        #pragma unroll
        for (int t = 0; t < 8; ++t) {
            *(short8*)&Bs[t * 2048 + tid * 8] =
                *(const short8*)&Wtf[t * 4096 + hf * 2048 + tid * 8];
        }
        __syncthreads();

        #pragma unroll
        for (int ksl = 0; ksl < 4; ++ksl) {
            int ko = (hf * 4 + ksl) * 32 + quad * 8;
            float4 a00 = *(const float4*)&xr0[ko];
            float4 a01 = *(const float4*)&xr0[ko + 4];
            float4 a10 = *(const float4*)&xr1[ko];
            float4 a11 = *(const float4*)&xr1[ko + 4];
            u32x4 u0, u1;
            u0.x = cvtpk(a00.x, a00.y);
            u0.y = cvtpk(a00.z, a00.w);
            u0.z = cvtpk(a01.x, a01.y);
            u0.w = cvtpk(a01.z, a01.w);
            u1.x = cvtpk(a10.x, a10.y);
            u1.y = cvtpk(a10.z, a10.w);
            u1.z = cvtpk(a11.x, a11.y);
            u1.w = cvtpk(a11.z, a11.w);
            short8 af0 = __builtin_bit_cast(short8, u0);
            short8 af1 = __builtin_bit_cast(short8, u1);
            #pragma unroll
            for (int t = 0; t < 8; ++t) {
                short8 bf = *(const short8*)&Bs[t * 2048 + ksl * 512 + lane * 8];
                acc[0][t] = __builtin_amdgcn_mfma_f32_16x16x32_bf16(af0, bf, acc[0][t], 0, 0, 0);
                acc[1][t] = __builtin_amdgcn_mfma_f32_16x16x32_bf16(af1, bf, acc[1][t], 0, 0, 0);
            }
        }
    }

    // h store: C/D layout col = t*16+ln, row = rt*16 + quad*4 + r.
    // Pair adjacent cols (ln even with ln+1, same quad) via shfl_down, store 4 B.
    bool evenln = (ln & 1) == 0;
    #pragma unroll
    for (int rt = 0; rt < 2; ++rt) {
        #pragma unroll
        for (int t = 0; t < 8; ++t) {
            #pragma unroll
            for (int r = 0; r < 4; ++r) {
                float v = acc[rt][t][r];
                float vn = __shfl_down(v, 1);
                int grow = row0w + rt * 16 + quad * 4 + r;
                if (evenln && grow < n) {
                    unsigned int pk = cvtpk(v, vn);
                    *(unsigned int*)&hb[(size_t)grow * 128 + t * 16 + ln] = pk;
                }
            }
        }
    }

    // fused attention halves
    #pragma unroll
    for (int hd = 0; hd < 4; ++hd) {
        float as1 = att_src[hd * 32 + ln];
        float as2 = att_src[hd * 32 + 16 + ln];
        float ad1 = att_dst[hd * 32 + ln];
        float ad2 = att_dst[hd * 32 + 16 + ln];
        #pragma unroll
        for (int rt = 0; rt < 2; ++rt) {
            #pragma unroll
            for (int r = 0; r < 4; ++r) {
                float ps = acc[rt][2 * hd][r] * as1 + acc[rt][2 * hd + 1][r] * as2;
                float pd = acc[rt][2 * hd][r] * ad1 + acc[rt][2 * hd + 1][r] * ad2;
                #pragma unroll
                for (int off = 1; off < 16; off <<= 1) {
                    ps += __shfl_xor(ps, off);
                    pd += __shfl_xor(pd, off);
                }
                if (ln == 0) {
                    int grow = row0w + rt * 16 + quad * 4 + r;
                    if (grow < n) {
                        a_src[grow * 4 + hd] = ps;
                        a_dst[grow * 4 + hd] = pd;
                    }
                }
            }
        }
    }
}

// Fused hist + padded-bucket scatter, int4-vectorized edge reads.
__global__ __launch_bounds__(256) void build_kernel(
    const int* __restrict__ src, const int* __restrict__ dst,
    int* __restrict__ deg, int* __restrict__ bucket, int e, int n) {
    int p = blockIdx.x & (NPART - 1);
    int slice = blockIdx.x >> 3;
    int nslices = gridDim.x >> 3;
    int part = (n + NPART - 1) / NPART;
    unsigned lo = (unsigned)(p * part);
    int e4 = e >> 2;
    int stride = nslices * 256;
    const int4* dst4 = (const int4*)dst;
    const int4* src4 = (const int4*)src;
    for (int i = slice * 256 + threadIdx.x; i < e4; i += stride) {
        int4 d4 = dst4[i];
        int4 s4 = src4[i];
        if ((unsigned)(d4.x - lo) < (unsigned)part) {
            int r = atomicAdd(&deg[d4.x], 1);
            if (r < CAP) bucket[d4.x * CAP + r] = s4.x;
        }
        if ((unsigned)(d4.y - lo) < (unsigned)part) {
            int r = atomicAdd(&deg[d4.y], 1);
            if (r < CAP) bucket[d4.y * CAP + r] = s4.y;
        }
        if ((unsigned)(d4.z - lo) < (unsigned)part) {
            int r = atomicAdd(&deg[d4.z], 1);
            if (r < CAP) bucket[d4.z * CAP + r] = s4.z;
        }
        if ((unsigned)(d4.w - lo) < (unsigned)part) {
            int r = atomicAdd(&deg[d4.w], 1);
            if (r < CAP) bucket[d4.w * CAP + r] = s4.w;
        }
    }
    if (blockIdx.x == 0 && threadIdx.x < (e & 3)) {
        int i = e4 * 4 + threadIdx.x;
        int d = dst[i];
        int r = atomicAdd(&deg[d], 1);
        if (r < CAP) bucket[d * CAP + r] = src[i];
    }
}

// One wave per destination node, two-phase.
// Phase 1: lane = (el=lane&15, hh=lane>>4) computes each logit once, reduces
// max/sum via shfl_xor over 16 el-lanes, writes normalized alpha + ids to LDS.
// Phase 2: pure gather+FMA, unrolled x8 for MLP.
__global__ __launch_bounds__(256) void aggregate_kernel(
    const unsigned short* __restrict__ hb, const float* __restrict__ a_src,
    const float* __restrict__ a_dst, const int* __restrict__ deg,
    const int* __restrict__ bucket, const float* __restrict__ bias,
    float* __restrict__ out, int n) {
    __shared__ float lds_alpha[4][CAP][4];  // [wave][edge][head]
    __shared__ int lds_s[4][CAP];
    int wave = threadIdx.x >> 6;
    int lane = threadIdx.x & 63;
    int node = blockIdx.x * 4 + wave;
    if (node >= n) node = n - 1;  // duplicate tail work; keeps barrier safe
    int el = lane & 15;
    int hh = lane >> 4;

    int cnt = deg[node];
    if (cnt > CAP) cnt = CAP;

    float adst = a_dst[node * 4 + hh];
    float e_self = lrelu(a_src[node * 4 + hh] + adst);

    float e_gp[4];
    int s_gp[4];
    float mloc = e_self;
    #pragma unroll
    for (int g = 0; g < 4; ++g) {
        int p = g * 16 + el;
        if (p < cnt) {
            int s = bucket[(unsigned)node * CAP + p];
            s_gp[g] = s;
            float ev = lrelu(a_src[s * 4 + hh] + adst);
            e_gp[g] = ev;
            mloc = fmaxf(mloc, ev);
        } else {
            s_gp[g] = node;
            e_gp[g] = -INFINITY;
        }
    }
    #pragma unroll
    for (int off = 1; off < 16; off <<= 1)
        mloc = fmaxf(mloc, __shfl_xor(mloc, off));

    float pe_gp[4];
    float dloc = 0.0f;
    #pragma unroll
    for (int g = 0; g < 4; ++g) {
        float pe = __expf(e_gp[g] - mloc);  // exp(-inf)=0 for masked slots
        pe_gp[g] = pe;
        dloc += pe;
    }
    #pragma unroll
    for (int off = 1; off < 16; off <<= 1)
        dloc += __shfl_xor(dloc, off);

    float pe_self = __expf(e_self - mloc);
    float inv = 1.0f / (dloc + pe_self);
    float alpha_self = pe_self * inv;

    #pragma unroll
    for (int g = 0; g < 4; ++g) {
        lds_alpha[wave][g * 16 + el][hh] = pe_gp[g] * inv;
        if (hh == 0) lds_s[wave][g * 16 + el] = s_gp[g];
    }
    __syncthreads();

    const unsigned int* hbu = (const unsigned int*)hb;
    float2 acc;
    {
        float2 hv = bfpair(hbu[(unsigned)node * 64u + lane]);
        acc.x = alpha_self * hv.x;
        acc.y = alpha_self * hv.y;
    }
    int p = 0;
    for (; p + 8 <= cnt; p += 8) {
        int4 sA = *(const int4*)&lds_s[wave][p];
        int4 sB = *(const int4*)&lds_s[wave][p + 4];
        unsigned int v0 = hbu[(unsigned)sA.x * 64u + lane];
        unsigned int v1 = hbu[(unsigned)sA.y * 64u + lane];
        unsigned int v2 = hbu[(unsigned)sA.z * 64u + lane];
        unsigned int v3 = hbu[(unsigned)sA.w * 64u + lane];
        unsigned int v4 = hbu[(unsigned)sB.x * 64u + lane];
        unsigned int v5 = hbu[(unsigned)sB.y * 64u + lane];
        unsigned int v6 = hbu[(unsigned)sB.z * 64u + lane];
        unsigned int v7 = hbu[(unsigned)sB.w * 64u + lane];
        float al0 = lds_alpha[wave][p + 0][hh];
        float al1 = lds_alpha[wave][p + 1][hh];
        float al2 = lds_alpha[wave][p + 2][hh];
        float al3 = lds_alpha[wave][p + 3][hh];
        float al4 = lds_alpha[wave][p + 4][hh];
        float al5 = lds_alpha[wave][p + 5][hh];
        float al6 = lds_alpha[wave][p + 6][hh];
        float al7 = lds_alpha[wave][p + 7][hh];
        float2 h0 = bfpair(v0), h1 = bfpair(v1), h2 = bfpair(v2), h3 = bfpair(v3);
        float2 h4 = bfpair(v4), h5 = bfpair(v5), h6 = bfpair(v6), h7 = bfpair(v7);
        acc.x += al0 * h0.x + al1 * h1.x + al2 * h2.x + al3 * h3.x
               + al4 * h4.x + al5 * h5.x + al6 * h6.x + al7 * h7.x;
        acc.y += al0 * h0.y + al1 * h1.y + al2 * h2.y + al3 * h3.y
               + al4 * h4.y + al5 * h5.y + al6 * h6.y + al7 * h7.y;
    }
    for (; p + 4 <= cnt; p += 4) {
        int4 sA = *(const int4*)&lds_s[wave][p];
        unsigned int v0 = hbu[(unsigned)sA.x * 64u + lane];
        unsigned int v1 = hbu[(unsigned)sA.y * 64u + lane];
        unsigned int v2 = hbu[(unsigned)sA.z * 64u + lane];
        unsigned int v3 = hbu[(unsigned)sA.w * 64u + lane];
        float al0 = lds_alpha[wave][p + 0][hh];
        float al1 = lds_alpha[wave][p + 1][hh];
        float al2 = lds_alpha[wave][p + 2][hh];
        float al3 = lds_alpha[wave][p + 3][hh];
        float2 h0 = bfpair(v0), h1 = bfpair(v1), h2 = bfpair(v2), h3 = bfpair(v3);
        acc.x += al0 * h0.x + al1 * h1.x + al2 * h2.x + al3 * h3.x;
        acc.y += al0 * h0.y + al1 * h1.y + al2 * h2.y + al3 * h3.y;
    }
    for (; p < cnt; ++p) {
        int s = lds_s[wave][p];
        float al = lds_alpha[wave][p][hh];
        float2 hv = bfpair(hbu[(unsigned)s * 64u + lane]);
        acc.x += al * hv.x;
        acc.y += al * hv.y;
    }

    int oc = hh * 32 + el * 2;
    float2 b2 = *(const float2*)&bias[oc];
    float2 o;
    o.x = acc.x + b2.x;
    o.y = acc.y + b2.y;
    *(float2*)&out[(size_t)node * 128 + oc] = o;
}

extern "C" void kernel_launch(void* const* d_in, const int* in_sizes, int n_in,
                              void* d_out, int out_size, void* d_ws, size_t ws_size,
                              hipStream_t stream) {
    const float* x = (const float*)d_in[0];
    const int* edge_index = (const int*)d_in[1];
    const float* W = (const float*)d_in[2];
    const float* att_src = (const float*)d_in[3];
    const float* att_dst = (const float*)d_in[4];
    const float* bias = (const float*)d_in[5];
    float* out = (float*)d_out;

    int n = in_sizes[0] / 256;   // 100000
    int e = in_sizes[1] / 2;     // 1600000
    const int* esrc = edge_index;
    const int* edst = edge_index + e;

    // workspace layout
    char* w = (char*)d_ws;
    unsigned short* hb = (unsigned short*)w;  w += (size_t)n * 128 * 2;   // bf16 h
    float* a_src = (float*)w;                 w += (size_t)n * 4 * 4;
    float* a_dst = (float*)w;                 w += (size_t)n * 4 * 4;
    unsigned short* Wtf = (unsigned short*)w; w += 128 * 256 * 2;
    int* deg = (int*)w;                       w += (size_t)n * 4;
    int* bucket = (int*)w;                    w += (size_t)n * CAP * 4;

    convW_kernel<<<128, 256, 0, stream>>>(W, Wtf, deg, n);
    gemm_fused_kernel<<<(n + 127) / 128, 256, 0, stream>>>(x, Wtf, att_src, att_dst,
                                                           hb, a_src, a_dst, n);
    build_kernel<<<256 * NPART, 256, 0, stream>>>(esrc, edst, deg, bucket, e, n);
    aggregate_kernel<<<(n + 3) / 4, 256, 0, stream>>>(hb, a_src, a_dst, deg,
                                                      bucket, bias, out, n);
}